// Round 8
// baseline (148.466 us; speedup 1.0000x reference)
//
#include <hip/hip_runtime.h>

// ---------------------------------------------------------------------------
// Downsampling — fp16 MFMA, XOR-swizzled LDS, DOUBLE-BUFFERED K-loop with
// fine-grained s_waitcnt vmcnt(6) (prefetch stays in flight across barrier).
//   prep:    M1T (even rows + odd>=961), M2T, A1 transpose       [9216 blocks]
//   gemm1:   fe{0,1}[8192][512]f16 = A1 @ (even rows of M1T)^T, K split 2x512
//   ola_pack: fr[4096][1024]f16 = frame(decimate(OLA(fe0+fe1)))
//   gemm2:   D[kk][n] = M2T @ fr^T ; coalesced float2 (Re,Im) epilogue.
// ---------------------------------------------------------------------------

#define WIN       1022
#define HOP       256
#define T_IN      127
#define NB        64
#define NPAD      1024
#define NE        512       // even-compacted stage-1 columns; K per z-slice
#define T_OUT     62
#define HALF_KEPT 16608     // 33216/2
#define L_USE     16638     // kept samples beyond 16637 feed no output frame
#define ROWS1     8128
#define ROWS1P    8192
#define ROWS2     3968
#define ROWS2P    4096
#define TWO_PI_F  6.28318530717958647692f

// s_waitcnt imm encodings (gfx9): vmcnt[3:0]|expcnt<<4|lgkmcnt<<8|vmcnt[5:4]<<14
#define WAIT_VM6   0x0F76   // vmcnt(6), exp/lgkm ignored
#define WAIT_VM0   0x0F70   // vmcnt(0), exp/lgkm ignored
#define WAIT_LGKM0 0xC07F   // lgkmcnt(0), vm/exp ignored

typedef _Float16 half8 __attribute__((ext_vector_type(8)));
typedef float    f32x4 __attribute__((ext_vector_type(4)));

// ------------------------------- fused prep --------------------------------
__global__ __launch_bounds__(256) void prep(const float* __restrict__ in,
                                            _Float16* __restrict__ M1T,
                                            _Float16* __restrict__ M2T,
                                            _Float16* __restrict__ A1) {
    __shared__ float lds[32 * 254];
    int bx = blockIdx.x, tid = threadIdx.x;
    const float cc = TWO_PI_F / (float)WIN;

    if (bx < 4096) {                       // ---- M1T[j][kk], irfft*synth
        int idx = bx * 256 + tid, j = idx >> 10, kk = idx & 1023;
        if ((j & 1) && j < 961) return;    // odd rows <961 never read
        float v = 0.f;
        if (j < WIN) {
            float w = 0.5f - 0.5f * __cosf(cc * (float)j);
            float dd = 0.f;
            int p = j & (HOP - 1);
            for (int r = 0; r < 4; ++r) {
                int ix = p + HOP * r;
                if (ix < WIN) {
                    float wi = 0.5f - 0.5f * __cosf(cc * (float)ix);
                    dd += wi * wi;
                }
            }
            float synth = w / dd;
            int k = kk >> 1, c = kk & 1;
            if (!(c == 1 && (k == 0 || k == 511))) {   // Im of DC/Nyquist ignored
                float a = (k == 0 || k == 511) ? (1.f / (float)WIN) : (2.f / (float)WIN);
                int m = (k * j) % WIN;                 // exact phase reduction
                float s, co;
                __sincosf((float)m * cc, &s, &co);
                v = a * synth * (c == 0 ? co : -s);
            }
        }
        M1T[idx] = (_Float16)v;
        return;
    }
    if (bx < 8192) {                       // ---- M2T[col][j], rfft*hann
        int idx = (bx - 4096) * 256 + tid, col = idx >> 10, j = idx & 1023;
        float v = 0.f;
        if (j < WIN) {
            float w = 0.5f - 0.5f * __cosf(cc * (float)j);
            int k = col >> 1, c = col & 1;
            int m = (k * j) % WIN;
            float s, co;
            __sincosf((float)m * cc, &s, &co);
            v = w * (c == 0 ? co : -s);
        }
        M2T[idx] = (_Float16)v;
        return;
    }
    // ---- pack_a: 1024 blocks (16 k-tiles x 64 batches)
    int bx2 = bx - 8192;
    int kt = bx2 >> 6, b = bx2 & 63;
    const float* base = in + ((size_t)b * 512 + kt * 32) * (T_IN * 2);
    for (int idx2 = tid; idx2 < 32 * 254; idx2 += 256)
        lds[idx2] = base[idx2];
    __syncthreads();
    for (int f = tid; f < T_IN * 64; f += 256) {
        int t = f >> 6, l = f & 63;
        int dk = l >> 1, c = l & 1;
        A1[(size_t)(b * T_IN + t) * NPAD + kt * 64 + l] =
            (_Float16)lds[dk * 254 + t * 2 + c];
    }
}

// ------------------------------- MFMA GEMM ---------------------------------
// 128x64 C-tile, BK=64, double-buffered LDS. gemm1: split-K (2 x 512).
// gemm2: A=M2T (M=1024 kk-rows), B=fr (N=3968 n-rows), full K=1024.
// LDS rows 64 halves; 8-half chunk u of row r at physical u^(r&7) (no bank
// conflicts). Staging contiguous: only the global source offset permutes.

__device__ __forceinline__ void stage16(const void* g, void* l) {
    __builtin_amdgcn_global_load_lds(
        (const __attribute__((address_space(1))) unsigned int*)g,
        (__attribute__((address_space(3))) unsigned int*)l, 16, 0, 0);
}

template <bool G2>
__global__ __launch_bounds__(256) void gemm_mfma(const _Float16* __restrict__ A,
                                                 const _Float16* __restrict__ B0,
                                                 void* __restrict__ Cv) {
    constexpr int BPITCH = G2 ? NPAD : 2 * NPAD;   // gemm1 B = even rows of M1T
    constexpr int KTOT   = G2 ? NPAD : NE;
    constexpr int NITER  = KTOT / 64;
    __shared__ __align__(16) _Float16 As[2][128 * 64];
    __shared__ __align__(16) _Float16 Bs[2][64 * 64];

    int tid  = threadIdx.x;
    int lane = tid & 63, wave = tid >> 6;
    int quad = lane >> 4, l16 = lane & 15;
    int rowOff = (wave >> 1) * 64, colOff = (wave & 1) * 32;
    int rowBase = blockIdx.y * 128, colBase = blockIdx.x * 64;
    int kbase = G2 ? 0 : blockIdx.z * NE;

    // staging: physical LDS chunk f (16 B) holds logical k-chunk (f&7)^(r&7)
    const _Float16* Ag[4]; int Alo[4];
    const _Float16* Bg[2]; int Blo[2];
#pragma unroll
    for (int u = 0; u < 4; ++u) {
        int f = u * 256 + tid, r = f >> 3, ko = (((f & 7) ^ (r & 7))) * 8;
        Ag[u] = A + (size_t)(rowBase + r) * NPAD + kbase + ko;
        Alo[u] = f * 8;
    }
#pragma unroll
    for (int u = 0; u < 2; ++u) {
        int f = u * 256 + tid, r = f >> 3, ko = (((f & 7) ^ (r & 7))) * 8;
        Bg[u] = B0 + (size_t)(colBase + r) * BPITCH + kbase + ko;
        Blo[u] = f * 8;
    }

    f32x4 acc[4][2] = {};

    // initial stage into buffer 0
#pragma unroll
    for (int u = 0; u < 4; ++u) stage16(Ag[u], &As[0][Alo[u]]);
#pragma unroll
    for (int u = 0; u < 2; ++u) stage16(Bg[u], &Bs[0][Blo[u]]);

    for (int it = 0; it < NITER; ++it) {
        int cur = it & 1, nxt = cur ^ 1;
        if (it + 1 < NITER) {
            int k1 = (it + 1) * 64;
#pragma unroll
            for (int u = 0; u < 4; ++u) stage16(Ag[u] + k1, &As[nxt][Alo[u]]);
#pragma unroll
            for (int u = 0; u < 2; ++u) stage16(Bg[u] + k1, &Bs[nxt][Blo[u]]);
            __builtin_amdgcn_s_waitcnt(WAIT_VM6);   // current tile done; prefetch in flight
        } else {
            __builtin_amdgcn_s_waitcnt(WAIT_VM0);
        }
        __builtin_amdgcn_s_barrier();

        half8 af[2][4], bf[2][2];
#pragma unroll
        for (int s = 0; s < 2; ++s) {
#pragma unroll
            for (int i = 0; i < 4; ++i) {
                int row = rowOff + i * 16 + l16;
                af[s][i] = *(const half8*)&As[cur][row * 64 + (((s * 4 + quad) ^ (row & 7)) * 8)];
            }
#pragma unroll
            for (int j = 0; j < 2; ++j) {
                int row = colOff + j * 16 + l16;
                bf[s][j] = *(const half8*)&Bs[cur][row * 64 + (((s * 4 + quad) ^ (row & 7)) * 8)];
            }
        }
#pragma unroll
        for (int s = 0; s < 2; ++s)
#pragma unroll
            for (int i = 0; i < 4; ++i)
#pragma unroll
                for (int j = 0; j < 2; ++j)
                    acc[i][j] = __builtin_amdgcn_mfma_f32_16x16x32_f16(af[s][i], bf[s][j], acc[i][j], 0, 0, 0);

        __builtin_amdgcn_s_waitcnt(WAIT_LGKM0);     // our ds_reads done
        __builtin_amdgcn_s_barrier();               // safe to overwrite cur next iter
    }

    // C/D layout: col = l16, row = quad*4 + reg
#pragma unroll
    for (int i = 0; i < 4; ++i) {
#pragma unroll
        for (int j = 0; j < 2; ++j) {
            int col = colBase + colOff + j * 16 + l16;
            if (!G2) {
                _Float16* fe = (_Float16*)Cv + (size_t)blockIdx.z * ROWS1P * NE;
#pragma unroll
                for (int rr = 0; rr < 4; ++rr) {
                    int row = rowBase + rowOff + i * 16 + quad * 4 + rr;
                    fe[(size_t)row * NE + col] = (_Float16)acc[i][j][rr];
                }
            } else {
                // col = n = b*62+t2 (all valid: grid.x=62); rows = kk pairs
                int b = col / T_OUT, t2 = col % T_OUT;
#pragma unroll
                for (int rr = 0; rr < 4; rr += 2) {
                    int row = rowBase + rowOff + i * 16 + quad * 4 + rr;  // even
                    int k = row >> 1;
                    float2 v = make_float2(acc[i][j][rr], acc[i][j][rr + 1]);
                    *(float2*)((float*)Cv + (((size_t)b * 512 + k) * T_OUT + t2) * 2) = v;
                }
            }
        }
    }
}

// ------------------------- fused OLA + decimate + frame --------------------
__global__ void ola_pack(const _Float16* __restrict__ fe0,
                         const _Float16* __restrict__ fe1,
                         const _Float16* __restrict__ A1,
                         const _Float16* __restrict__ M1T,
                         _Float16* __restrict__ fr) {
    int i = blockIdx.x * 256 + threadIdx.x;
    int b = blockIdx.y;
    if (i >= L_USE) return;

    float v = 0.f;
    if (i < HALF_KEPT) {                   // s = 2i even: compacted OLA
        int tmin = (i > 510) ? ((i - 383) >> 7) : 0;
        int tmax = i >> 7; if (tmax > T_IN - 1) tmax = T_IN - 1;
        for (int t = tmin; t <= tmax; ++t) {
            size_t idx = (size_t)(b * T_IN + t) * NE + (i - t * 128);
            v += (float)fe0[idx] + (float)fe1[idx];
        }
    } else {                               // tail: only t=126 contributes
        int s = i + HALF_KEPT;             // 33216..33245
        int p = s - 32256;                 // 960..989
        if (!(s & 1)) {
            size_t idx = (size_t)(b * T_IN + 126) * NE + (p >> 1);
            v = (float)fe0[idx] + (float)fe1[idx];
        } else {                           // odd p: direct 1024-dot
            const _Float16* ar = A1 + (size_t)(b * T_IN + 126) * NPAD;
            const _Float16* mr = M1T + (size_t)p * NPAD;
            float a0 = 0.f;
            for (int k = 0; k < NPAD; k += 8) {
                half8 av = *(const half8*)&ar[k];
                half8 mv = *(const half8*)&mr[k];
#pragma unroll
                for (int u = 0; u < 8; ++u)
                    a0 += (float)av[u] * (float)mv[u];
            }
            v = a0;
        }
    }

    _Float16 hv = (_Float16)v;
    int t2min = (i > WIN - 1) ? ((i - (WIN - 1) + HOP - 1) >> 8) : 0;
    int t2max = i >> 8; if (t2max > T_OUT - 1) t2max = T_OUT - 1;
    for (int t2 = t2min; t2 <= t2max; ++t2)
        fr[(size_t)(b * T_OUT + t2) * NPAD + (i - t2 * HOP)] = hv;
}

// ------------------------------- launcher ----------------------------------

extern "C" void kernel_launch(void* const* d_in, const int* in_sizes, int n_in,
                              void* d_out, int out_size, void* d_ws, size_t ws_size,
                              hipStream_t stream) {
    const float* in = (const float*)d_in[0];
    float* out = (float*)d_out;
    char* ws = (char*)d_ws;

    _Float16* M1T = (_Float16*)ws;                        // 2 MB
    _Float16* M2T = M1T + (size_t)NPAD * NPAD;            // 2 MB
    _Float16* A1  = M2T + (size_t)NPAD * NPAD;            // 16 MB
    _Float16* fr  = A1 + (size_t)ROWS1P * NPAD;           // 8 MB
    _Float16* fe  = fr + (size_t)ROWS2P * NPAD;           // 8+8 MB (z=0,1)

    prep<<<9216, 256, 0, stream>>>(in, M1T, M2T, A1);
    gemm_mfma<false><<<dim3(NE / 64, ROWS1P / 128, 2), 256, 0, stream>>>(A1, M1T, fe);
    ola_pack<<<dim3(65, NB), 256, 0, stream>>>(fe, fe + (size_t)ROWS1P * NE, A1, M1T, fr);
    // gemm2: A=M2T (kk rows), B=fr (n rows); x over n=3968 (62 tiles), y over kk
    gemm_mfma<true><<<dim3(ROWS2 / 64, NPAD / 128), 256, 0, stream>>>(M2T, fr, out);
}

// Round 9
// 147.155 us; speedup vs baseline: 1.0089x; 1.0089x over previous
//
#include <hip/hip_runtime.h>

// ---------------------------------------------------------------------------
// Downsampling — fp16 MFMA, XOR-swizzled LDS, single-buffered (dbuf measured
// neutral-to-worse).  Kernel sum ~35 µs; dur_us additionally carries ~110 µs
// of harness re-poison/restore (268 MB d_ws fill each timed iter).
//   prep:    M1T rows {even 0..1022, odd 961..1021}, M2T, A1 transpose
//   gemm1:   fe{0,1}[8192][512]f16 = A1 @ (even rows of M1T)^T, K split 2x512
//   ola_pack: fr[4096][1024]f16 = frame(decimate(OLA(fe0+fe1)))
//   gemm2:   D[kk][n] = M2T @ fr^T ; coalesced float2 (Re,Im) epilogue.
// ---------------------------------------------------------------------------

#define WIN       1022
#define HOP       256
#define T_IN      127
#define NB        64
#define NPAD      1024
#define NE        512       // even-compacted stage-1 columns; K per z-slice
#define T_OUT     62
#define HALF_KEPT 16608     // 33216/2
#define L_USE     16638     // kept samples beyond 16637 feed no output frame
#define ROWS1     8128
#define ROWS1P    8192
#define ROWS2     3968
#define ROWS2P    4096
#define TWO_PI_F  6.28318530717958647692f

// prep grid layout: M1T rows = 512 even (j=2r, incl. zero row 1022) + 31 odd
// (j=961+2(r-512)) = 543 rows -> 543*1024/256 = 2172 blocks.
#define M1_BLOCKS  2172
#define M2_BLOCKS  4096
#define PACK_BASE  (M1_BLOCKS + M2_BLOCKS)     // 6268
#define PREP_BLOCKS (PACK_BASE + 1024)         // 7292

typedef _Float16 half8 __attribute__((ext_vector_type(8)));
typedef float    f32x4 __attribute__((ext_vector_type(4)));

// ------------------------------- fused prep --------------------------------
__global__ __launch_bounds__(256) void prep(const float* __restrict__ in,
                                            _Float16* __restrict__ M1T,
                                            _Float16* __restrict__ M2T,
                                            _Float16* __restrict__ A1) {
    __shared__ float lds[32 * 254];
    int bx = blockIdx.x, tid = threadIdx.x;
    const float cc = TWO_PI_F / (float)WIN;

    if (bx < M1_BLOCKS) {                  // ---- M1T[j][kk], irfft*synth
        int idx = bx * 256 + tid;
        int r = idx >> 10, kk = idx & 1023;
        int j = (r < 512) ? (2 * r) : (961 + 2 * (r - 512));
        float v = 0.f;
        if (j < WIN) {
            float w = 0.5f - 0.5f * __cosf(cc * (float)j);
            float dd = 0.f;
            int p = j & (HOP - 1);
            for (int rr = 0; rr < 4; ++rr) {
                int ix = p + HOP * rr;
                if (ix < WIN) {
                    float wi = 0.5f - 0.5f * __cosf(cc * (float)ix);
                    dd += wi * wi;
                }
            }
            float synth = w / dd;
            int k = kk >> 1, c = kk & 1;
            if (!(c == 1 && (k == 0 || k == 511))) {   // Im of DC/Nyquist ignored
                int m = (k * j) % WIN;                 // exact phase reduction
                float s, co;
                __sincosf((float)m * cc, &s, &co);
                float a = (k == 0 || k == 511) ? (1.f / (float)WIN) : (2.f / (float)WIN);
                v = a * synth * (c == 0 ? co : -s);
            }
        }
        M1T[(size_t)j * NPAD + kk] = (_Float16)v;      // j=1022 row written as 0
        return;
    }
    if (bx < PACK_BASE) {                  // ---- M2T[col][j], rfft*hann
        int idx = (bx - M1_BLOCKS) * 256 + tid, col = idx >> 10, j = idx & 1023;
        float v = 0.f;
        if (j < WIN) {
            float w = 0.5f - 0.5f * __cosf(cc * (float)j);
            int k = col >> 1, c = col & 1;
            int m = (k * j) % WIN;
            float s, co;
            __sincosf((float)m * cc, &s, &co);
            v = w * (c == 0 ? co : -s);
        }
        M2T[idx] = (_Float16)v;
        return;
    }
    // ---- pack_a: 1024 blocks (16 k-tiles x 64 batches)
    int bx2 = bx - PACK_BASE;
    int kt = bx2 >> 6, b = bx2 & 63;
    const float* base = in + ((size_t)b * 512 + kt * 32) * (T_IN * 2);
    for (int idx2 = tid; idx2 < 32 * 254; idx2 += 256)
        lds[idx2] = base[idx2];
    __syncthreads();
    for (int f = tid; f < T_IN * 64; f += 256) {
        int t = f >> 6, l = f & 63;
        int dk = l >> 1, c = l & 1;
        A1[(size_t)(b * T_IN + t) * NPAD + kt * 64 + l] =
            (_Float16)lds[dk * 254 + t * 2 + c];
    }
}

// ------------------------------- MFMA GEMM ---------------------------------
// 128x64 C-tile, BK=64, single-buffered. gemm1: split-K (2 x 512).
// gemm2: A=M2T (M=1024 kk-rows), B=fr (N=3968 n-rows), full K=1024.
// LDS rows 64 halves; 8-half chunk u of row r at physical u^(r&7) (no bank
// conflicts). Staging contiguous: only the global source offset permutes.

__device__ __forceinline__ void stage16(const void* g, void* l) {
    __builtin_amdgcn_global_load_lds(
        (const __attribute__((address_space(1))) unsigned int*)g,
        (__attribute__((address_space(3))) unsigned int*)l, 16, 0, 0);
}

template <bool G2>
__global__ __launch_bounds__(256) void gemm_mfma(const _Float16* __restrict__ A,
                                                 const _Float16* __restrict__ B0,
                                                 void* __restrict__ Cv) {
    constexpr int BPITCH = G2 ? NPAD : 2 * NPAD;   // gemm1 B = even rows of M1T
    constexpr int KTOT   = G2 ? NPAD : NE;
    __shared__ __align__(16) _Float16 As[128 * 64];
    __shared__ __align__(16) _Float16 Bs[64 * 64];

    int tid  = threadIdx.x;
    int lane = tid & 63, wave = tid >> 6;
    int quad = lane >> 4, l16 = lane & 15;
    int rowOff = (wave >> 1) * 64, colOff = (wave & 1) * 32;
    int rowBase = blockIdx.y * 128, colBase = blockIdx.x * 64;
    int kbase = G2 ? 0 : blockIdx.z * NE;

    // staging: physical LDS chunk f (16 B) holds logical k-chunk (f&7)^(r&7)
    const _Float16* Ag[4]; int Alo[4];
    const _Float16* Bg[2]; int Blo[2];
#pragma unroll
    for (int u = 0; u < 4; ++u) {
        int f = u * 256 + tid, r = f >> 3, ko = (((f & 7) ^ (r & 7))) * 8;
        Ag[u] = A + (size_t)(rowBase + r) * NPAD + kbase + ko;
        Alo[u] = f * 8;
    }
#pragma unroll
    for (int u = 0; u < 2; ++u) {
        int f = u * 256 + tid, r = f >> 3, ko = (((f & 7) ^ (r & 7))) * 8;
        Bg[u] = B0 + (size_t)(colBase + r) * BPITCH + kbase + ko;
        Blo[u] = f * 8;
    }

    f32x4 acc[4][2] = {};

    for (int k0 = 0; k0 < KTOT; k0 += 64) {
#pragma unroll
        for (int u = 0; u < 4; ++u) stage16(Ag[u] + k0, &As[Alo[u]]);
#pragma unroll
        for (int u = 0; u < 2; ++u) stage16(Bg[u] + k0, &Bs[Blo[u]]);
        __syncthreads();

        half8 af[2][4], bf[2][2];
#pragma unroll
        for (int s = 0; s < 2; ++s) {
#pragma unroll
            for (int i = 0; i < 4; ++i) {
                int row = rowOff + i * 16 + l16;
                af[s][i] = *(const half8*)&As[row * 64 + (((s * 4 + quad) ^ (row & 7)) * 8)];
            }
#pragma unroll
            for (int j = 0; j < 2; ++j) {
                int row = colOff + j * 16 + l16;
                bf[s][j] = *(const half8*)&Bs[row * 64 + (((s * 4 + quad) ^ (row & 7)) * 8)];
            }
        }
#pragma unroll
        for (int s = 0; s < 2; ++s)
#pragma unroll
            for (int i = 0; i < 4; ++i)
#pragma unroll
                for (int j = 0; j < 2; ++j)
                    acc[i][j] = __builtin_amdgcn_mfma_f32_16x16x32_f16(af[s][i], bf[s][j], acc[i][j], 0, 0, 0);
        __syncthreads();
    }

    // C/D layout: col = l16, row = quad*4 + reg
#pragma unroll
    for (int i = 0; i < 4; ++i) {
#pragma unroll
        for (int j = 0; j < 2; ++j) {
            int col = colBase + colOff + j * 16 + l16;
            if (!G2) {
                _Float16* fe = (_Float16*)Cv + (size_t)blockIdx.z * ROWS1P * NE;
#pragma unroll
                for (int rr = 0; rr < 4; ++rr) {
                    int row = rowBase + rowOff + i * 16 + quad * 4 + rr;
                    fe[(size_t)row * NE + col] = (_Float16)acc[i][j][rr];
                }
            } else {
                // col = n = b*62+t2 (all valid: grid.x=62); rows = kk pairs
                int b = col / T_OUT, t2 = col % T_OUT;
#pragma unroll
                for (int rr = 0; rr < 4; rr += 2) {
                    int row = rowBase + rowOff + i * 16 + quad * 4 + rr;  // even
                    int k = row >> 1;
                    float2 v = make_float2(acc[i][j][rr], acc[i][j][rr + 1]);
                    *(float2*)((float*)Cv + (((size_t)b * 512 + k) * T_OUT + t2) * 2) = v;
                }
            }
        }
    }
}

// ------------------------- fused OLA + decimate + frame --------------------
__global__ void ola_pack(const _Float16* __restrict__ fe0,
                         const _Float16* __restrict__ fe1,
                         const _Float16* __restrict__ A1,
                         const _Float16* __restrict__ M1T,
                         _Float16* __restrict__ fr) {
    int i = blockIdx.x * 256 + threadIdx.x;
    int b = blockIdx.y;
    if (i >= L_USE) return;

    float v = 0.f;
    if (i < HALF_KEPT) {                   // s = 2i even: compacted OLA
        int tmin = (i > 510) ? ((i - 383) >> 7) : 0;
        int tmax = i >> 7; if (tmax > T_IN - 1) tmax = T_IN - 1;
        for (int t = tmin; t <= tmax; ++t) {
            size_t idx = (size_t)(b * T_IN + t) * NE + (i - t * 128);
            v += (float)fe0[idx] + (float)fe1[idx];
        }
    } else {                               // tail: only t=126 contributes
        int s = i + HALF_KEPT;             // 33216..33245
        int p = s - 32256;                 // 960..989
        if (!(s & 1)) {
            size_t idx = (size_t)(b * T_IN + 126) * NE + (p >> 1);
            v = (float)fe0[idx] + (float)fe1[idx];
        } else {                           // odd p: direct 1024-dot
            const _Float16* ar = A1 + (size_t)(b * T_IN + 126) * NPAD;
            const _Float16* mr = M1T + (size_t)p * NPAD;
            float a0 = 0.f;
            for (int k = 0; k < NPAD; k += 8) {
                half8 av = *(const half8*)&ar[k];
                half8 mv = *(const half8*)&mr[k];
#pragma unroll
                for (int u = 0; u < 8; ++u)
                    a0 += (float)av[u] * (float)mv[u];
            }
            v = a0;
        }
    }

    _Float16 hv = (_Float16)v;
    int t2min = (i > WIN - 1) ? ((i - (WIN - 1) + HOP - 1) >> 8) : 0;
    int t2max = i >> 8; if (t2max > T_OUT - 1) t2max = T_OUT - 1;
    for (int t2 = t2min; t2 <= t2max; ++t2)
        fr[(size_t)(b * T_OUT + t2) * NPAD + (i - t2 * HOP)] = hv;
}

// ------------------------------- launcher ----------------------------------

extern "C" void kernel_launch(void* const* d_in, const int* in_sizes, int n_in,
                              void* d_out, int out_size, void* d_ws, size_t ws_size,
                              hipStream_t stream) {
    const float* in = (const float*)d_in[0];
    float* out = (float*)d_out;
    char* ws = (char*)d_ws;

    _Float16* M1T = (_Float16*)ws;                        // 2 MB
    _Float16* M2T = M1T + (size_t)NPAD * NPAD;            // 2 MB
    _Float16* A1  = M2T + (size_t)NPAD * NPAD;            // 16 MB
    _Float16* fr  = A1 + (size_t)ROWS1P * NPAD;           // 8 MB
    _Float16* fe  = fr + (size_t)ROWS2P * NPAD;           // 8+8 MB (z=0,1)

    prep<<<PREP_BLOCKS, 256, 0, stream>>>(in, M1T, M2T, A1);
    gemm_mfma<false><<<dim3(NE / 64, ROWS1P / 128, 2), 256, 0, stream>>>(A1, M1T, fe);
    ola_pack<<<dim3(65, NB), 256, 0, stream>>>(fe, fe + (size_t)ROWS1P * NE, A1, M1T, fr);
    // gemm2: A=M2T (kk rows), B=fr (n rows); x over n=3968 (62 tiles), y over kk
    gemm_mfma<true><<<dim3(ROWS2 / 64, NPAD / 128), 256, 0, stream>>>(M2T, fr, out);
}